// Round 3
// baseline (16356.715 us; speedup 1.0000x reference)
//
#include <hip/hip_runtime.h>
#include <stdint.h>

// Problem constants
#define B_ 8
#define C_ 512
#define H_ 4096
#define HB 256          // H / BLOCKS
#define NB 15           // BLOCKS - 1
#define CUT_ 8
#define M_ 2048         // CUT_ * HB
#define NEG (-1e9f)
#define INV_TEMP (1.0f/0.7f)

// Workspace layout (float offsets)
#define SQ_OFF   0          // [B][3840] block-means of q
#define SK_OFF   30720      // [B][3840]
#define ST_OFF   61440      // [B][2] sum, sumsq
#define PERM_OFF 61456      // [B][15][15]
#define KCUT_OFF 65536      // [B][C][M] = 8388608 floats
#define VCUT_OFF (65536 + 8388608)
#define WS_FLOATS (65536 + 2*8388608)

// ---------------- threefry2x32 (exact JAX semantics, key=(0,42)) -------------
__device__ __forceinline__ unsigned rotl32(unsigned x, unsigned n) {
    return (x << n) | (x >> (32u - n));
}
__device__ __forceinline__ void threefry2x32(unsigned k0, unsigned k1,
                                             unsigned x0, unsigned x1,
                                             unsigned &o0, unsigned &o1) {
    unsigned k2 = 0x1BD11BDAu ^ k0 ^ k1;
    x0 += k0; x1 += k1;
    x0+=x1; x1=rotl32(x1,13); x1^=x0;
    x0+=x1; x1=rotl32(x1,15); x1^=x0;
    x0+=x1; x1=rotl32(x1,26); x1^=x0;
    x0+=x1; x1=rotl32(x1, 6); x1^=x0;
    x0+=k1; x1+=k2+1u;
    x0+=x1; x1=rotl32(x1,17); x1^=x0;
    x0+=x1; x1=rotl32(x1,29); x1^=x0;
    x0+=x1; x1=rotl32(x1,16); x1^=x0;
    x0+=x1; x1=rotl32(x1,24); x1^=x0;
    x0+=k2; x1+=k0+2u;
    x0+=x1; x1=rotl32(x1,13); x1^=x0;
    x0+=x1; x1=rotl32(x1,15); x1^=x0;
    x0+=x1; x1=rotl32(x1,26); x1^=x0;
    x0+=x1; x1=rotl32(x1, 6); x1^=x0;
    x0+=k0; x1+=k1+3u;
    x0+=x1; x1=rotl32(x1,17); x1^=x0;
    x0+=x1; x1=rotl32(x1,29); x1^=x0;
    x0+=x1; x1=rotl32(x1,16); x1^=x0;
    x0+=x1; x1=rotl32(x1,24); x1^=x0;
    x0+=k1; x1+=k2+4u;
    x0+=x1; x1=rotl32(x1,13); x1^=x0;
    x0+=x1; x1=rotl32(x1,15); x1^=x0;
    x0+=x1; x1=rotl32(x1,26); x1^=x0;
    x0+=x1; x1=rotl32(x1, 6); x1^=x0;
    x0+=k2; x1+=k0+5u;
    o0 = x0; o1 = x1;
}

// ---------------- Kernel 1: per-(b,h) channel means of q,k -------------------
__global__ void colmean_kernel(const float* __restrict__ q, const float* __restrict__ k,
                               float* __restrict__ sq, float* __restrict__ sk) {
    int id  = blockIdx.x * 256 + threadIdx.x;   // 0 .. 245759
    int h   = id % 3840;
    int rest= id / 3840;
    int b   = rest % 8;
    int seg = rest / 8;                          // 0..7
    int c0  = seg * 64;
    const float* qb = q + ((size_t)b*C_ + c0) * H_ + h;
    const float* kb = k + ((size_t)b*C_ + c0) * H_ + h;
    float aq = 0.f, ak = 0.f;
    #pragma unroll 8
    for (int c = 0; c < 64; c++) {
        aq += qb[(size_t)c * H_];
        ak += kb[(size_t)c * H_];
    }
    atomicAdd(&sq[b*3840 + h], aq * (1.0f/512.0f));
    atomicAdd(&sk[b*3840 + h], ak * (1.0f/512.0f));
}

// ---------------- Kernel 2: R -> gumbel -> sinkhorn -> perm ------------------
__global__ void perm_kernel(const float* __restrict__ sqg, const float* __restrict__ skg,
                            float* __restrict__ perm) {
    int b = blockIdx.x;
    int tid = threadIdx.x;
    __shared__ float sqs[NB*HB];
    __shared__ float sks[NB*HB];
    __shared__ float mat[NB][16];
    __shared__ float lse[NB];
    for (int i = tid; i < NB*HB; i += 256) {
        sqs[i] = sqg[b*3840 + i];
        sks[i] = skg[b*3840 + i];
    }
    __syncthreads();
    int i = tid / 15, j = tid % 15;
    if (tid < 225) {
        float acc = 0.f;
        for (int h = 0; h < HB; h++) acc += sqs[i*HB + h] * sks[j*HB + h];
        float R = acc * 0.044194173824159216f;   // C^-0.5
        float r0 = (R > 0.0f) ? logf(R) : NEG;
        int g = (b*15 + i)*15 + j;               // flat index in [0,1800)
        // JAX modern partitionable path (_threefry_random_bits_partitionable):
        //   counts1, counts2 = iota_2x32_shape(shape)      -> (hi=0, lo=g)
        //   bits1, bits2 = threefry2x32(key, counts1, counts2)
        //   bit_width in [8,16,32]: bits = bits1 ^ bits2   <- XOR of halves
        unsigned o0, o1;
        threefry2x32(0u, 42u, 0u, (unsigned)g, o0, o1);
        unsigned bits = o0 ^ o1;
        float u = __uint_as_float((bits >> 9) | 0x3f800000u) - 1.0f;
        float gum = -logf(-logf(u + 1e-6f) + 1e-6f);
        mat[i][j] = (r0 + gum) * INV_TEMP;
    }
    __syncthreads();
    for (int it = 0; it < 8; it++) {
        if (tid < 15) {  // rows: logsumexp over j (axis=2)
            float m = -3.4e38f;
            for (int jj = 0; jj < 15; jj++) m = fmaxf(m, mat[tid][jj]);
            float s = 0.f;
            for (int jj = 0; jj < 15; jj++) s += expf(mat[tid][jj] - m);
            lse[tid] = m + logf(s);
        }
        __syncthreads();
        if (tid < 225) mat[i][j] -= lse[i];
        __syncthreads();
        if (tid < 15) {  // cols: logsumexp over i (axis=1)
            float m = -3.4e38f;
            for (int ii = 0; ii < 15; ii++) m = fmaxf(m, mat[ii][tid]);
            float s = 0.f;
            for (int ii = 0; ii < 15; ii++) s += expf(mat[ii][tid] - m);
            lse[tid] = m + logf(s);
        }
        __syncthreads();
        if (tid < 225) mat[i][j] -= lse[j];
        __syncthreads();
    }
    if (tid < 225) perm[b*225 + tid] = expf(mat[i][j]);
}

// ---------------- Kernel 3: build K_cut^T, V_cut^T  [B][C][M] ----------------
__global__ void cut_kernel(const float* __restrict__ k, const float* __restrict__ v,
                           const float* __restrict__ perm,
                           float* __restrict__ kcutT, float* __restrict__ vcutT) {
    int bc = blockIdx.x;            // b*512 + c
    int b = bc >> 9;
    int h = threadIdx.x;            // 0..255
    __shared__ float pl[NB][CUT_];
    if (threadIdx.x < NB*CUT_) {
        int n = threadIdx.x / CUT_, j = threadIdx.x % CUT_;
        pl[n][j] = perm[b*225 + n*15 + j];
    }
    __syncthreads();
    float ak[CUT_] = {0,0,0,0,0,0,0,0};
    float av[CUT_] = {0,0,0,0,0,0,0,0};
    const float* kb = k + (size_t)bc * H_ + h;
    const float* vb = v + (size_t)bc * H_ + h;
    #pragma unroll
    for (int n = 0; n < NB; n++) {
        float kv_ = kb[n*HB];
        float vv_ = vb[n*HB];
        #pragma unroll
        for (int j = 0; j < CUT_; j++) { ak[j] += kv_ * pl[n][j]; av[j] += vv_ * pl[n][j]; }
    }
    size_t obase = (size_t)bc * M_ + h;
    #pragma unroll
    for (int j = 0; j < CUT_; j++) {
        kcutT[obase + j*HB] = ak[j];
        vcutT[obase + j*HB] = av[j];
    }
}

// ---------------- Kernel 4: flash attention (fp32) + stats -------------------
#define CST 516          // LDS row stride for 512-wide K/V tiles (pad 4)
__global__ __launch_bounds__(256)
void attn_kernel(const float* __restrict__ q, const float* __restrict__ kcutT,
                 const float* __restrict__ vcutT, float* __restrict__ out,
                 float* __restrict__ stats) {
    int blk = blockIdx.x;
    int b   = blk >> 7;            // /128
    int h0  = (blk & 127) * 32;
    int tid = threadIdx.x;
    int tc  = tid & 15;
    int tr  = tid >> 4;
    __shared__ float kv[8320];     // max(16*516, 32*260)
    __shared__ float red[256], red2[256];

    // ---- stage Q tile into registers via LDS bounce (coalesced global reads)
    float4 qr0[8], qr1[8];
    for (int ch = 0; ch < 2; ch++) {
        __syncthreads();
        for (int it = 0; it < 32; it++) {
            int idx = tid + it*256;              // 0..8191
            int r = idx & 31, cc = idx >> 5;     // 32 rows x 256 ch chunk
            kv[r*260 + cc] = q[((size_t)b*C_ + ch*256 + cc) * H_ + h0 + r];
        }
        __syncthreads();
        #pragma unroll
        for (int u2 = 0; u2 < 4; u2++) {
            int uu = ch*4 + u2;
            int cc = tc*4 + 64*u2;               // within-chunk channel
            qr0[uu] = *(const float4*)&kv[ tr      *260 + cc];
            qr1[uu] = *(const float4*)&kv[(tr+16)*260 + cc];
        }
    }

    float4 O0[8], O1[8];
    #pragma unroll
    for (int u = 0; u < 8; u++) { O0[u] = make_float4(0,0,0,0); O1[u] = make_float4(0,0,0,0); }
    float m0r = -3.4e38f, m1r = -3.4e38f, l0r = 0.f, l1r = 0.f;

    const size_t kbase = (size_t)b * C_ * M_;
    for (int t0 = 0; t0 < M_/16; t0++) {
        int mi = t0 * 16;
        __syncthreads();                          // kv free
        for (int it = 0; it < 32; it++) {         // K tile: kv[j][c]
            int idx = tid + it*256;
            int j = idx & 15, c = idx >> 4;
            kv[j*CST + c] = kcutT[kbase + (size_t)c*M_ + mi + j];
        }
        __syncthreads();
        // ---- S = Q K^T / TEMP, reduced over 16 lane c-slices
        float s0[16], s1[16];
        #pragma unroll
        for (int j = 0; j < 16; j++) {
            const float* kr = &kv[j*CST + tc*4];
            float p0 = 0.f, p1 = 0.f;
            #pragma unroll
            for (int u = 0; u < 8; u++) {
                float4 kx = *(const float4*)(kr + 64*u);
                p0 += qr0[u].x*kx.x + qr0[u].y*kx.y + qr0[u].z*kx.z + qr0[u].w*kx.w;
                p1 += qr1[u].x*kx.x + qr1[u].y*kx.y + qr1[u].z*kx.z + qr1[u].w*kx.w;
            }
            #pragma unroll
            for (int msk = 1; msk < 16; msk <<= 1) {
                p0 += __shfl_xor(p0, msk, 16);
                p1 += __shfl_xor(p1, msk, 16);
            }
            s0[j] = p0 * INV_TEMP;
            s1[j] = p1 * INV_TEMP;
        }
        // ---- online softmax (register-local; all 16 lanes of a row agree)
        float mn0 = m0r, mn1 = m1r;
        #pragma unroll
        for (int j = 0; j < 16; j++) { mn0 = fmaxf(mn0, s0[j]); mn1 = fmaxf(mn1, s1[j]); }
        float al0 = expf(m0r - mn0), al1 = expf(m1r - mn1);
        float ps0 = 0.f, ps1 = 0.f;
        #pragma unroll
        for (int j = 0; j < 16; j++) {
            s0[j] = expf(s0[j] - mn0); ps0 += s0[j];   // s[] now holds P
            s1[j] = expf(s1[j] - mn1); ps1 += s1[j];
        }
        l0r = l0r*al0 + ps0;  m0r = mn0;
        l1r = l1r*al1 + ps1;  m1r = mn1;
        #pragma unroll
        for (int u = 0; u < 8; u++) {
            O0[u].x*=al0; O0[u].y*=al0; O0[u].z*=al0; O0[u].w*=al0;
            O1[u].x*=al1; O1[u].y*=al1; O1[u].z*=al1; O1[u].w*=al1;
        }
        __syncthreads();                          // done reading K
        for (int it = 0; it < 32; it++) {         // V tile overwrites kv
            int idx = tid + it*256;
            int j = idx & 15, c = idx >> 4;
            kv[j*CST + c] = vcutT[kbase + (size_t)c*M_ + mi + j];
        }
        __syncthreads();
        // ---- O += P V
        #pragma unroll
        for (int j = 0; j < 16; j++) {
            const float* vr = &kv[j*CST + tc*4];
            float pa = s0[j], pb = s1[j];
            #pragma unroll
            for (int u = 0; u < 8; u++) {
                float4 vx = *(const float4*)(vr + 64*u);
                O0[u].x += pa*vx.x; O0[u].y += pa*vx.y; O0[u].z += pa*vx.z; O0[u].w += pa*vx.w;
                O1[u].x += pb*vx.x; O1[u].y += pb*vx.y; O1[u].z += pb*vx.z; O1[u].w += pb*vx.w;
            }
        }
    }
    // ---- epilogue: normalize, store, per-block stats
    float inv0 = 1.0f / l0r, inv1 = 1.0f / l1r;
    float ls = 0.f, lss = 0.f;
    size_t ob0 = ((size_t)b*H_ + h0 + tr    ) * C_;
    size_t ob1 = ((size_t)b*H_ + h0 + tr + 16) * C_;
    #pragma unroll
    for (int u = 0; u < 8; u++) {
        float4 a = O0[u]; a.x*=inv0; a.y*=inv0; a.z*=inv0; a.w*=inv0;
        float4 c = O1[u]; c.x*=inv1; c.y*=inv1; c.z*=inv1; c.w*=inv1;
        *(float4*)&out[ob0 + tc*4 + 64*u] = a;
        *(float4*)&out[ob1 + tc*4 + 64*u] = c;
        ls  += a.x+a.y+a.z+a.w + c.x+c.y+c.z+c.w;
        lss += a.x*a.x+a.y*a.y+a.z*a.z+a.w*a.w + c.x*c.x+c.y*c.y+c.z*c.z+c.w*c.w;
    }
    red[tid] = ls; red2[tid] = lss;
    __syncthreads();
    for (int s = 128; s > 0; s >>= 1) {
        if (tid < s) { red[tid] += red[tid+s]; red2[tid] += red2[tid+s]; }
        __syncthreads();
    }
    if (tid == 0) {
        atomicAdd(&stats[b*2    ], red[0]);
        atomicAdd(&stats[b*2 + 1], red2[0]);
    }
}

// ---------------- Kernel 5: instance norm (in place on d_out) ----------------
__global__ void norm_kernel(float* __restrict__ out, const float* __restrict__ stats) {
    size_t i = (size_t)blockIdx.x * 256 + threadIdx.x;   // float4 index
    int b = (int)(i >> 19);                              // 524288 float4 per batch
    float4 vv = ((float4*)out)[i];
    const float inv = 1.0f / (4096.0f * 512.0f);
    float mu  = stats[b*2] * inv;
    float var = stats[b*2 + 1] * inv - mu*mu;
    float rs  = rsqrtf(var + 1e-5f);
    vv.x = (vv.x - mu) * rs;
    vv.y = (vv.y - mu) * rs;
    vv.z = (vv.z - mu) * rs;
    vv.w = (vv.w - mu) * rs;
    ((float4*)out)[i] = vv;
}

extern "C" void kernel_launch(void* const* d_in, const int* in_sizes, int n_in,
                              void* d_out, int out_size, void* d_ws, size_t ws_size,
                              hipStream_t stream) {
    const float* q = (const float*)d_in[0];
    const float* k = (const float*)d_in[1];
    const float* v = (const float*)d_in[2];
    float* out = (float*)d_out;
    float* ws  = (float*)d_ws;
    if (ws_size < (size_t)WS_FLOATS * sizeof(float)) return;  // need ~67.4 MB scratch

    float* sq    = ws + SQ_OFF;
    float* sk    = ws + SK_OFF;
    float* stats = ws + ST_OFF;
    float* perm  = ws + PERM_OFF;
    float* kcutT = ws + KCUT_OFF;
    float* vcutT = ws + VCUT_OFF;

    // zero sq/sk accumulators + stats (re-poisoned to 0xAA before every call)
    hipMemsetAsync(d_ws, 0, (size_t)PERM_OFF * sizeof(float), stream);

    colmean_kernel<<<960, 256, 0, stream>>>(q, k, sq, sk);
    perm_kernel   <<<8,   256, 0, stream>>>(sq, sk, perm);
    cut_kernel    <<<4096,256, 0, stream>>>(k, v, perm, kcutT, vcutT);
    attn_kernel   <<<1024,256, 0, stream>>>(q, kcutT, vcutT, out, stats);
    norm_kernel   <<<16384,256,0, stream>>>(out, stats);
}

// Round 4
// 1101.105 us; speedup vs baseline: 14.8548x; 14.8548x over previous
//
#include <hip/hip_runtime.h>
#include <stdint.h>

typedef _Float16 half_t;
typedef _Float16 half8 __attribute__((ext_vector_type(8)));
typedef float floatx4 __attribute__((ext_vector_type(4)));

#define B_ 8
#define C_ 512
#define H_ 4096
#define HB 256
#define NB 15
#define CUT_ 8
#define M_ 2048
#define INV_TEMP (1.0f/0.7f)
#define NEG (-1e9f)

// Workspace layout (bytes)
#define SQ_OFFB   0u            // B*3840 floats
#define SK_OFFB   122880u
#define ST_OFFB   245760u       // B*2 floats
#define PERM_OFFB 245824u       // B*225 floats
#define KC16_OFFB 262144u       // [B][M][C] fp16 = 16.8 MB
#define VC16_OFFB (262144u + 16777216u)   // [B][C][M] fp16
#define WS_NEED   (262144u + 2u*16777216u)

// ---------------- threefry2x32 (JAX partitionable, key=(0,42)) ---------------
__device__ __forceinline__ unsigned rotl32(unsigned x, unsigned n) {
    return (x << n) | (x >> (32u - n));
}
__device__ __forceinline__ void threefry2x32(unsigned k0, unsigned k1,
                                             unsigned x0, unsigned x1,
                                             unsigned &o0, unsigned &o1) {
    unsigned k2 = 0x1BD11BDAu ^ k0 ^ k1;
    x0 += k0; x1 += k1;
    x0+=x1; x1=rotl32(x1,13); x1^=x0;
    x0+=x1; x1=rotl32(x1,15); x1^=x0;
    x0+=x1; x1=rotl32(x1,26); x1^=x0;
    x0+=x1; x1=rotl32(x1, 6); x1^=x0;
    x0+=k1; x1+=k2+1u;
    x0+=x1; x1=rotl32(x1,17); x1^=x0;
    x0+=x1; x1=rotl32(x1,29); x1^=x0;
    x0+=x1; x1=rotl32(x1,16); x1^=x0;
    x0+=x1; x1=rotl32(x1,24); x1^=x0;
    x0+=k2; x1+=k0+2u;
    x0+=x1; x1=rotl32(x1,13); x1^=x0;
    x0+=x1; x1=rotl32(x1,15); x1^=x0;
    x0+=x1; x1=rotl32(x1,26); x1^=x0;
    x0+=x1; x1=rotl32(x1, 6); x1^=x0;
    x0+=k0; x1+=k1+3u;
    x0+=x1; x1=rotl32(x1,17); x1^=x0;
    x0+=x1; x1=rotl32(x1,29); x1^=x0;
    x0+=x1; x1=rotl32(x1,16); x1^=x0;
    x0+=x1; x1=rotl32(x1,24); x1^=x0;
    x0+=k1; x1+=k2+4u;
    x0+=x1; x1=rotl32(x1,13); x1^=x0;
    x0+=x1; x1=rotl32(x1,15); x1^=x0;
    x0+=x1; x1=rotl32(x1,26); x1^=x0;
    x0+=x1; x1=rotl32(x1, 6); x1^=x0;
    x0+=k2; x1+=k0+5u;
    o0 = x0; o1 = x1;
}

// ---------------- Kernel 1: per-(b,h) channel means of q,k -------------------
__global__ void colmean_kernel(const float* __restrict__ q, const float* __restrict__ k,
                               float* __restrict__ sq, float* __restrict__ sk) {
    int id  = blockIdx.x * 256 + threadIdx.x;
    int h   = id % 3840;
    int rest= id / 3840;
    int b   = rest % 8;
    int seg = rest / 8;
    int c0  = seg * 64;
    const float* qb = q + ((size_t)b*C_ + c0) * H_ + h;
    const float* kb = k + ((size_t)b*C_ + c0) * H_ + h;
    float aq = 0.f, ak = 0.f;
    #pragma unroll 8
    for (int c = 0; c < 64; c++) {
        aq += qb[(size_t)c * H_];
        ak += kb[(size_t)c * H_];
    }
    atomicAdd(&sq[b*3840 + h], aq * (1.0f/512.0f));
    atomicAdd(&sk[b*3840 + h], ak * (1.0f/512.0f));
}

// ---------------- Kernel 2: R -> gumbel -> sinkhorn -> perm ------------------
__global__ void perm_kernel(const float* __restrict__ sqg, const float* __restrict__ skg,
                            float* __restrict__ perm) {
    int b = blockIdx.x;
    int tid = threadIdx.x;
    __shared__ float sqs[NB*HB];
    __shared__ float sks[NB*HB];
    __shared__ float mat[NB][16];
    __shared__ float lse[NB];
    for (int i = tid; i < NB*HB; i += 256) {
        sqs[i] = sqg[b*3840 + i];
        sks[i] = skg[b*3840 + i];
    }
    __syncthreads();
    int i = tid / 15, j = tid % 15;
    if (tid < 225) {
        float acc = 0.f;
        for (int h = 0; h < HB; h++) acc += sqs[i*HB + h] * sks[j*HB + h];
        float R = acc * 0.044194173824159216f;
        float r0 = (R > 0.0f) ? logf(R) : NEG;
        int g = (b*15 + i)*15 + j;
        unsigned o0, o1;
        threefry2x32(0u, 42u, 0u, (unsigned)g, o0, o1);
        unsigned bits = o0 ^ o1;
        float u = __uint_as_float((bits >> 9) | 0x3f800000u) - 1.0f;
        float gum = -logf(-logf(u + 1e-6f) + 1e-6f);
        mat[i][j] = (r0 + gum) * INV_TEMP;
    }
    __syncthreads();
    for (int it = 0; it < 8; it++) {
        if (tid < 15) {
            float m = -3.4e38f;
            for (int jj = 0; jj < 15; jj++) m = fmaxf(m, mat[tid][jj]);
            float s = 0.f;
            for (int jj = 0; jj < 15; jj++) s += expf(mat[tid][jj] - m);
            lse[tid] = m + logf(s);
        }
        __syncthreads();
        if (tid < 225) mat[i][j] -= lse[i];
        __syncthreads();
        if (tid < 15) {
            float m = -3.4e38f;
            for (int ii = 0; ii < 15; ii++) m = fmaxf(m, mat[ii][tid]);
            float s = 0.f;
            for (int ii = 0; ii < 15; ii++) s += expf(mat[ii][tid] - m);
            lse[tid] = m + logf(s);
        }
        __syncthreads();
        if (tid < 225) mat[i][j] -= lse[j];
        __syncthreads();
    }
    if (tid < 225) perm[b*225 + tid] = expf(mat[i][j]);
}

// ---------------- Kernel 3a: K_cut fp16  [b][m][c]  (LDS-tiled transpose) ----
// kc[b][j*HB+h][c] = sum_n k[b][c][n*HB+h]*perm[n][j]
__global__ __launch_bounds__(256)
void kcut_kernel(const float* __restrict__ k, const float* __restrict__ perm,
                 half_t* __restrict__ kc) {
    int bid = blockIdx.x;            // (b 8, hchunk 8, chalf 2) = 128
    int b = bid >> 4;
    int hch = (bid >> 1) & 7;
    int chalf = bid & 1;
    int h0 = hch * 32;
    int tid = threadIdx.x;
    __shared__ float kt[32*481];     // [c' 32][n 15][h' 32], c-stride 481 (pad)
    __shared__ float pl[NB][CUT_];
    if (tid < NB*CUT_) pl[tid/CUT_][tid%CUT_] = perm[b*225 + (tid/CUT_)*15 + (tid%CUT_)];
    int cp = tid & 31;
    int hg = tid >> 5;               // 0..7 -> h' = hg*4+q
    for (int ct = 0; ct < 8; ct++) {
        int c0 = chalf*256 + ct*32;
        __syncthreads();
        for (int it = 0; it < 15; it++) {
            int slot = tid + it*256;         // 0..3839
            int h4 = slot & 7;
            int n  = (slot >> 3) % 15;
            int cc = slot / 120;
            float4 vv = *(const float4*)&k[((size_t)(b*C_ + c0 + cc))*H_ + n*HB + h0 + h4*4];
            *(float4*)&kt[cc*481 + n*32 + h4*4] = vv;
        }
        __syncthreads();
        float acc[CUT_][4];
        #pragma unroll
        for (int j = 0; j < CUT_; j++) { acc[j][0]=0.f; acc[j][1]=0.f; acc[j][2]=0.f; acc[j][3]=0.f; }
        #pragma unroll
        for (int n = 0; n < NB; n++) {
            float kv0 = kt[cp*481 + n*32 + hg*4 + 0];
            float kv1 = kt[cp*481 + n*32 + hg*4 + 1];
            float kv2 = kt[cp*481 + n*32 + hg*4 + 2];
            float kv3 = kt[cp*481 + n*32 + hg*4 + 3];
            #pragma unroll
            for (int j = 0; j < CUT_; j++) {
                float p = pl[n][j];
                acc[j][0] += kv0*p; acc[j][1] += kv1*p; acc[j][2] += kv2*p; acc[j][3] += kv3*p;
            }
        }
        #pragma unroll
        for (int j = 0; j < CUT_; j++)
            for (int q2 = 0; q2 < 4; q2++) {
                int m = j*HB + h0 + hg*4 + q2;
                kc[((size_t)b*M_ + m)*C_ + c0 + cp] = (half_t)acc[j][q2];
            }
    }
}

// ---------------- Kernel 3b: V_cut fp16  [b][c][m]  (coalesced) --------------
__global__ __launch_bounds__(256)
void vcut_kernel(const float* __restrict__ v, const float* __restrict__ perm,
                 half_t* __restrict__ vc) {
    int bc = blockIdx.x;             // b*512 + c
    int b = bc >> 9;
    int h = threadIdx.x;
    __shared__ float pl[NB][CUT_];
    if (h < NB*CUT_) pl[h/CUT_][h%CUT_] = perm[b*225 + (h/CUT_)*15 + (h%CUT_)];
    __syncthreads();
    const float* vb = v + (size_t)bc * H_ + h;
    float av[CUT_] = {0,0,0,0,0,0,0,0};
    #pragma unroll
    for (int n = 0; n < NB; n++) {
        float vv = vb[n*HB];
        #pragma unroll
        for (int j = 0; j < CUT_; j++) av[j] += vv * pl[n][j];
    }
    #pragma unroll
    for (int j = 0; j < CUT_; j++)
        vc[(size_t)bc*M_ + j*HB + h] = (half_t)av[j];
}

// ---------------- Kernel 4: flash attention, fp16 MFMA -----------------------
// grid 512: batch = bid&7 (XCD affinity), htile = bid>>3; 64 q-rows/block.
// 8 waves: wm = w&3 (16-row m-group), wc = w>>2 (256-ch c-slice).
// QK^T 2-pass (q split hi+lo fp16 vs fp16 K). Flash online softmax.
__global__ __launch_bounds__(512, 2)
void attn_kernel(const float* __restrict__ q, const half_t* __restrict__ kc,
                 const half_t* __restrict__ vc, float* __restrict__ out,
                 float* __restrict__ stats) {
    __shared__ half_t ktile[2][32][520];   // [key][c], row pad 8 halves
    __shared__ half_t vtile[512][40];      // [c][key], row pad 8 halves
    __shared__ float  spart[2][64][33];    // [wc][row][key] partial S
    __shared__ half_t pslab[64][40];       // [row][key] P fp16
    __shared__ float  qstage[64][68];      // [h][c-chunk 64]
    __shared__ float  redbuf[8][2];

    int bid = blockIdx.x;
    int b   = bid & 7;
    int h0  = (bid >> 3) * 64;
    int tid = threadIdx.x;
    int w    = tid >> 6;
    int lane = tid & 63;
    int lm   = lane & 15;
    int quad = lane >> 4;
    int wm = w & 3;
    int wc = w >> 2;

    // ---- stage Q (fp32) and build hi/lo fp16 A-fragments --------------------
    half8 qhi[8], qlo[8];
    for (int ch = 0; ch < 8; ch++) {
        int c0 = ch * 64;
        __syncthreads();
        #pragma unroll
        for (int it = 0; it < 2; it++) {
            int slot = tid + it*512;        // 0..1023
            int cc = slot >> 4;
            int h4 = slot & 15;
            float4 qv = *(const float4*)&q[((size_t)(b*C_ + c0 + cc))*H_ + h0 + h4*4];
            qstage[h4*4+0][cc] = qv.x;
            qstage[h4*4+1][cc] = qv.y;
            qstage[h4*4+2][cc] = qv.z;
            qstage[h4*4+3][cc] = qv.w;
        }
        __syncthreads();
        if ((ch >> 2) == wc) {
            int row = 16*wm + lm;
            #pragma unroll
            for (int kk = 0; kk < 2; kk++) {
                int kb = (ch & 3)*2 + kk;
                const float* qp = &qstage[row][kk*32 + quad*8];
                float4 a = *(const float4*)qp;
                float4 c4 = *(const float4*)(qp + 4);
                float vals[8] = {a.x,a.y,a.z,a.w,c4.x,c4.y,c4.z,c4.w};
                half8 hh, hl;
                #pragma unroll
                for (int j = 0; j < 8; j++) {
                    half_t h1 = (half_t)vals[j];
                    hh[j] = h1;
                    hl[j] = (half_t)(vals[j] - (float)h1);
                }
                qhi[kb] = hh; qlo[kb] = hl;
            }
        }
    }

    floatx4 O[16];
    #pragma unroll
    for (int n = 0; n < 16; n++) O[n] = (floatx4)0.f;
    float ms[4] = {-3.4e38f,-3.4e38f,-3.4e38f,-3.4e38f};
    float ls[4] = {0.f,0.f,0.f,0.f};

    const half_t* kbase = kc + (size_t)b*M_*C_;
    const half_t* vbase = vc + (size_t)b*C_*M_;

    // staging index precompute
    int krow = tid >> 4;                 // 0..31
    int kc16 = tid & 15;                 // 16B-chunk within row
    float4 kreg[4], vreg[4];

    // prologue: K(0) direct into ktile[0]
    {
        const half_t* kg = kbase + (size_t)krow*C_ + kc16*32;
        #pragma unroll
        for (int i = 0; i < 4; i++) {
            float4 t = *(const float4*)(kg + i*8);
            *(float4*)&ktile[0][krow][kc16*32 + i*8] = t;
        }
        // prefetch K(1), V(0)
        const half_t* kg1 = kbase + (size_t)(32 + krow)*C_ + kc16*32;
        const half_t* vg0 = vbase + (size_t)tid*M_;
        #pragma unroll
        for (int i = 0; i < 4; i++) { kreg[i] = *(const float4*)(kg1 + i*8); vreg[i] = *(const float4*)(vg0 + i*8); }
    }

    int buf = 0;
    for (int t = 0; t < 64; t++) {
        __syncthreads();   // B0: K(t) visible, vtile/pslab free, prefetches drained
        // write staged V(t); write K(t+1) into other buffer
        #pragma unroll
        for (int i = 0; i < 4; i++) *(float4*)&vtile[tid][i*8] = vreg[i];
        if (t + 1 < 64) {
            #pragma unroll
            for (int i = 0; i < 4; i++) *(float4*)&ktile[buf^1][krow][kc16*32 + i*8] = kreg[i];
        }
        // ---- QK^T partial over this wave's 256-ch slice
        floatx4 acc0 = (floatx4)0.f, acc1 = (floatx4)0.f;
        #pragma unroll
        for (int kb = 0; kb < 8; kb++) {
            int coff = 256*wc + 32*kb + quad*8;
            half8 b0 = *(const half8*)&ktile[buf][lm][coff];
            half8 b1 = *(const half8*)&ktile[buf][16 + lm][coff];
            acc0 = __builtin_amdgcn_mfma_f32_16x16x32_f16(qhi[kb], b0, acc0, 0, 0, 0);
            acc0 = __builtin_amdgcn_mfma_f32_16x16x32_f16(qlo[kb], b0, acc0, 0, 0, 0);
            acc1 = __builtin_amdgcn_mfma_f32_16x16x32_f16(qhi[kb], b1, acc1, 0, 0, 0);
            acc1 = __builtin_amdgcn_mfma_f32_16x16x32_f16(qlo[kb], b1, acc1, 0, 0, 0);
        }
        int rbase = 16*wm + quad*4;
        #pragma unroll
        for (int r = 0; r < 4; r++) {
            spart[wc][rbase + r][lm]      = acc0[r];
            spart[wc][rbase + r][16 + lm] = acc1[r];
        }
        __syncthreads();   // B1: partials visible; ktile[buf] reads done
        // ---- reduce + online softmax (C-layout; identical across wc)
        float p0[4], p1[4], alpha[4];
        #pragma unroll
        for (int r = 0; r < 4; r++) {
            float s0 = (spart[0][rbase+r][lm]      + spart[1][rbase+r][lm])      * INV_TEMP;
            float s1 = (spart[0][rbase+r][16+lm]   + spart[1][rbase+r][16+lm])   * INV_TEMP;
            float mx = fmaxf(s0, s1);
            #pragma unroll
            for (int msk = 1; msk < 16; msk <<= 1) mx = fmaxf(mx, __shfl_xor(mx, msk, 16));
            float mn = fmaxf(ms[r], mx);
            alpha[r] = expf(ms[r] - mn);
            p0[r] = expf(s0 - mn);
            p1[r] = expf(s1 - mn);
            float ps = p0[r] + p1[r];
            #pragma unroll
            for (int msk = 1; msk < 16; msk <<= 1) ps += __shfl_xor(ps, msk, 16);
            ls[r] = ls[r]*alpha[r] + ps;
            ms[r] = mn;
        }
        #pragma unroll
        for (int n = 0; n < 16; n++) {
            #pragma unroll
            for (int r = 0; r < 4; r++) O[n][r] *= alpha[r];
        }
        if (wc == 0) {
            #pragma unroll
            for (int r = 0; r < 4; r++) {
                pslab[rbase + r][lm]      = (half_t)p0[r];
                pslab[rbase + r][16 + lm] = (half_t)p1[r];
            }
        }
        __syncthreads();   // B2: P visible
        // prefetch next-tile global data (drained at next B0, covered by PV)
        if (t + 1 < 64) {
            const half_t* vg = vbase + (size_t)tid*M_ + (t+1)*32;
            #pragma unroll
            for (int i = 0; i < 4; i++) vreg[i] = *(const float4*)(vg + i*8);
        }
        if (t + 2 < 64) {
            const half_t* kg = kbase + (size_t)((t+2)*32 + krow)*C_ + kc16*32;
            #pragma unroll
            for (int i = 0; i < 4; i++) kreg[i] = *(const float4*)(kg + i*8);
        }
        // ---- PV
        half8 pa = *(const half8*)&pslab[16*wm + lm][quad*8];
        #pragma unroll
        for (int n = 0; n < 16; n++) {
            half8 vb = *(const half8*)&vtile[256*wc + 16*n + lm][quad*8];
            O[n] = __builtin_amdgcn_mfma_f32_16x16x32_f16(pa, vb, O[n], 0, 0, 0);
        }
        buf ^= 1;
    }

    // ---- epilogue: normalize, store, instance-norm stats
    float inv[4];
    #pragma unroll
    for (int r = 0; r < 4; r++) inv[r] = 1.0f / ls[r];
    float sa = 0.f, sb = 0.f;
    int rowg = h0 + 16*wm + quad*4;
    #pragma unroll
    for (int n = 0; n < 16; n++) {
        #pragma unroll
        for (int r = 0; r < 4; r++) {
            float o = O[n][r] * inv[r];
            out[((size_t)b*H_ + rowg + r)*C_ + 256*wc + 16*n + lm] = o;
            sa += o; sb += o*o;
        }
    }
    #pragma unroll
    for (int msk = 1; msk < 64; msk <<= 1) {
        sa += __shfl_xor(sa, msk, 64);
        sb += __shfl_xor(sb, msk, 64);
    }
    if (lane == 0) { redbuf[w][0] = sa; redbuf[w][1] = sb; }
    __syncthreads();
    if (tid == 0) {
        float a = 0.f, c2 = 0.f;
        for (int w2 = 0; w2 < 8; w2++) { a += redbuf[w2][0]; c2 += redbuf[w2][1]; }
        atomicAdd(&stats[b*2    ], a);
        atomicAdd(&stats[b*2 + 1], c2);
    }
}

// ---------------- Kernel 5: instance norm (in place on d_out) ----------------
__global__ void norm_kernel(float* __restrict__ out, const float* __restrict__ stats) {
    size_t i = (size_t)blockIdx.x * 256 + threadIdx.x;
    int b = (int)(i >> 19);
    float4 vv = ((float4*)out)[i];
    const float inv = 1.0f / (4096.0f * 512.0f);
    float mu  = stats[b*2] * inv;
    float var = stats[b*2 + 1] * inv - mu*mu;
    float rs  = rsqrtf(var + 1e-5f);
    vv.x = (vv.x - mu) * rs;
    vv.y = (vv.y - mu) * rs;
    vv.z = (vv.z - mu) * rs;
    vv.w = (vv.w - mu) * rs;
    ((float4*)out)[i] = vv;
}

extern "C" void kernel_launch(void* const* d_in, const int* in_sizes, int n_in,
                              void* d_out, int out_size, void* d_ws, size_t ws_size,
                              hipStream_t stream) {
    const float* q = (const float*)d_in[0];
    const float* k = (const float*)d_in[1];
    const float* v = (const float*)d_in[2];
    float* out = (float*)d_out;
    if (ws_size < (size_t)WS_NEED) return;

    float*  sq    = (float*) ((char*)d_ws + SQ_OFFB);
    float*  sk    = (float*) ((char*)d_ws + SK_OFFB);
    float*  stats = (float*) ((char*)d_ws + ST_OFFB);
    float*  perm  = (float*) ((char*)d_ws + PERM_OFFB);
    half_t* kc    = (half_t*)((char*)d_ws + KC16_OFFB);
    half_t* vc    = (half_t*)((char*)d_ws + VC16_OFFB);

    hipMemsetAsync(d_ws, 0, (size_t)KC16_OFFB, stream);

    colmean_kernel<<<960,  256, 0, stream>>>(q, k, sq, sk);
    perm_kernel   <<<8,    256, 0, stream>>>(sq, sk, perm);
    kcut_kernel   <<<128,  256, 0, stream>>>(k, perm, kc);
    vcut_kernel   <<<4096, 256, 0, stream>>>(v, perm, vc);
    attn_kernel   <<<512,  512, 0, stream>>>(q, kc, vc, out, stats);
    norm_kernel   <<<16384,256, 0, stream>>>(out, stats);
}